// Round 5
// baseline (278.513 us; speedup 1.0000x reference)
//
#include <hip/hip_runtime.h>

typedef short short8 __attribute__((ext_vector_type(8)));
typedef float floatx4 __attribute__((ext_vector_type(4)));
typedef float floatx16 __attribute__((ext_vector_type(16)));
typedef unsigned short ushort4v __attribute__((ext_vector_type(4)));

#define DEV static __device__ __forceinline__

// fp32 -> bf16 round-to-nearest-even
DEV unsigned short f2bf(float f) {
  unsigned int u = __builtin_bit_cast(unsigned int, f);
  u += 0x7fffu + ((u >> 16) & 1u);
  return (unsigned short)(u >> 16);
}

// pack two fp32 -> bf16x2 (round-half-up; P values positive, bias ~0.5 ulp)
DEV unsigned int pkbf2(float a, float b) {
  unsigned int ua = __builtin_bit_cast(unsigned int, a) + 0x8000u;
  unsigned int ub = __builtin_bit_cast(unsigned int, b) + 0x8000u;
  return (ua >> 16) | (ub & 0xffff0000u);
}

// async global->LDS, 16B per lane (dest = wave-uniform base + lane*16)
DEV void gload16(const unsigned short* g, unsigned short* l) {
  __builtin_amdgcn_global_load_lds((__attribute__((address_space(1))) void*)g,
                                   (__attribute__((address_space(3))) void*)l,
                                   16, 0, 0);
}

// ---------------------------------------------------------------------------
// Kernel 1: fused fp32->bf16 convert (blocks 0..8191) + maskpack (8192..8703)
// ---------------------------------------------------------------------------
__global__ void prep_kernel(const float* __restrict__ hs, const float* __restrict__ Wq,
                            const float* __restrict__ Wk, const float* __restrict__ Wv,
                            const float* __restrict__ Wo, const int* __restrict__ mask,
                            unsigned short* __restrict__ xbf, unsigned short* __restrict__ wqkv,
                            unsigned short* __restrict__ wobf,
                            unsigned long long* __restrict__ bits) {
  const int bid = blockIdx.x;
  if (bid < 8192) {
    size_t i4 = ((size_t)bid * 256 + threadIdx.x) * 4;
    const float* src;
    unsigned short* dst;
    if (i4 < 4194304) {
      src = hs + i4; dst = xbf + i4;
    } else if (i4 < 7340032) {
      size_t o = i4 - 4194304;
      size_t lo = o & 1048575;
      src = (o < 1048576) ? (Wq + lo) : ((o < 2097152) ? (Wk + lo) : (Wv + lo));
      dst = wqkv + o;
    } else {
      size_t o = i4 - 7340032;
      src = Wo + o; dst = wobf + o;
    }
    float4 v = *(const float4*)src;
    ushort4v u;
    u.x = f2bf(v.x); u.y = f2bf(v.y); u.z = f2bf(v.z); u.w = f2bf(v.w);
    *(ushort4v*)dst = u;
  } else {
    int w = (bid - 8192) * 256 + threadIdx.x;  // 131072 words
    const int4* p = (const int4*)(mask + (size_t)w * 64);
    unsigned long long r = 0ull;
#pragma unroll
    for (int j = 0; j < 16; ++j) {
      int4 m = p[j];
      r |= (unsigned long long)(m.x != 0) << (j * 4 + 0);
      r |= (unsigned long long)(m.y != 0) << (j * 4 + 1);
      r |= (unsigned long long)(m.z != 0) << (j * 4 + 2);
      r |= (unsigned long long)(m.w != 0) << (j * 4 + 3);
    }
    bits[w] = r;
  }
}

// ---------------------------------------------------------------------------
// Kernel 2: fused QKV projection. 128x128 tile, BK=32, 4 waves (2x2).
//   nb<16 (Q,K): swapped orientation C^T = W·X^T -> packed 8B stores to [b,h,s,d].
//     Q additionally pre-scaled by 1/sqrt(64)*log2(e) for the attn kernel.
//   nb>=16 (V): normal orientation -> packed 8B stores to V^T [b,h,d,s].
// ---------------------------------------------------------------------------
__global__ void __launch_bounds__(256) qkv_gemm(
    const unsigned short* __restrict__ X, const unsigned short* __restrict__ W,
    const float* __restrict__ bq, const float* __restrict__ bk, const float* __restrict__ bv,
    unsigned short* __restrict__ Qb, unsigned short* __restrict__ Kb,
    unsigned short* __restrict__ Vt) {
  __shared__ __align__(16) unsigned short As[128 * 32];
  __shared__ __align__(16) unsigned short Bs[128 * 32];
  const int tid = threadIdx.x;
  const int lane = tid & 63, wv = tid >> 6;
  const int wm = wv >> 1, wn = wv & 1;
  const int quad = lane >> 4, l15 = lane & 15;
  const int mb = blockIdx.y, nb = blockIdx.x;
  const bool sw = (nb < 16);  // Q/K blocks: swapped operand orientation

  const unsigned short* ga = X + (size_t)(mb * 128 + (tid >> 2)) * 1024 + (tid & 3) * 8;
  const unsigned short* gb = W + (size_t)(nb * 128 + (tid >> 2)) * 1024 + (tid & 3) * 8;
  unsigned short* la1 = As + tid * 8;
  unsigned short* la2 = As + 2048 + tid * 8;
  unsigned short* lb1 = Bs + tid * 8;
  unsigned short* lb2 = Bs + 2048 + tid * 8;

  const int wx = sw ? wn : wm;  // X-tile row block
  const int ww = sw ? wm : wn;  // W-tile row block

  floatx4 acc[4][4] = {};
  for (int kt = 0; kt < 32; ++kt) {
    const int k0 = kt * 32;
    gload16(ga + k0, la1);
    gload16(ga + k0 + 65536, la2);   // +64 rows
    gload16(gb + k0, lb1);
    gload16(gb + k0 + 65536, lb2);
    __syncthreads();
    short8 xa[4], wb[4];
#pragma unroll
    for (int i = 0; i < 4; ++i) {
      xa[i] = *(const short8*)&As[(wx * 64 + i * 16 + l15) * 32 + quad * 8];
      wb[i] = *(const short8*)&Bs[(ww * 64 + i * 16 + l15) * 32 + quad * 8];
    }
    if (sw) {
#pragma unroll
      for (int mt = 0; mt < 4; ++mt)
#pragma unroll
        for (int nt = 0; nt < 4; ++nt)
          acc[mt][nt] = __builtin_amdgcn_mfma_f32_16x16x32_bf16(wb[mt], xa[nt], acc[mt][nt], 0, 0, 0);
    } else {
#pragma unroll
      for (int mt = 0; mt < 4; ++mt)
#pragma unroll
        for (int nt = 0; nt < 4; ++nt)
          acc[mt][nt] = __builtin_amdgcn_mfma_f32_16x16x32_bf16(xa[mt], wb[nt], acc[mt][nt], 0, 0, 0);
    }
    __syncthreads();
  }

  if (sw) {
    // rows (m) = W-cols, cols (n) = s. d varies along r -> packed 8B stores.
#pragma unroll
    for (int mt = 0; mt < 4; ++mt) {
      const int wc0 = nb * 128 + wm * 64 + mt * 16 + quad * 4;  // W-col for r=0
      const int mat = wc0 >> 10;          // 0=Q, 1=K
      const int nl0 = wc0 & 1023;
      const int hh = nl0 >> 6, d0 = nl0 & 63;
      const float4 b4 = *(const float4*)((mat ? bk : bq) + nl0);
      const float scl = mat ? 1.0f : 0.180336879f;  // Q pre-scale: log2(e)/8
      unsigned short* dst = mat ? Kb : Qb;
#pragma unroll
      for (int nt = 0; nt < 4; ++nt) {
        const int colx = mb * 128 + wn * 64 + nt * 16 + l15;    // s index
        const int bb = colx >> 11, s = colx & 2047;
        ushort4v pv;
        pv[0] = f2bf((acc[mt][nt][0] + b4.x) * scl);
        pv[1] = f2bf((acc[mt][nt][1] + b4.y) * scl);
        pv[2] = f2bf((acc[mt][nt][2] + b4.z) * scl);
        pv[3] = f2bf((acc[mt][nt][3] + b4.w) * scl);
        *(ushort4v*)&dst[((size_t)(bb * 16 + hh) * 2048 + s) * 64 + d0] = pv;
      }
    }
  } else {
    // V: normal orientation; s varies along r -> packed 8B stores into V^T.
#pragma unroll
    for (int nt = 0; nt < 4; ++nt) {
      const int col = nb * 128 + wn * 64 + nt * 16 + l15;  // in [2048,3072)
      const int nl = col & 1023;
      const float bias = bv[nl];
      const int hh = nl >> 6, d = nl & 63;
#pragma unroll
      for (int mt = 0; mt < 4; ++mt) {
        const int row0 = mb * 128 + wm * 64 + mt * 16 + quad * 4;
        const int bb = row0 >> 11, s = row0 & 2047;
        ushort4v pv;
#pragma unroll
        for (int r = 0; r < 4; ++r) pv[r] = f2bf(acc[mt][nt][r] + bias);
        *(ushort4v*)&Vt[((size_t)(bb * 16 + hh) * 64 + d) * 2048 + s] = pv;
      }
    }
  }
}

// ---------------------------------------------------------------------------
// Kernel 3: flash attention, pipelined. 512 blocks = 32 (b,h) x 16 q-tiles of
//   128 rows; 4 waves x 32 q-rows. Double-buffered LDS (2 x (Ks 16KB + Vs
//   16KB) = 64KB). Per iter: ds_write staged regs -> ONE barrier -> prefetch
//   next tile (after barrier so the vmcnt(0) drain never waits on it) ->
//   compute. Softmax: Q pre-scaled, accs seeded with -10 (shift-invariant);
//   row-sum accumulated by MFMA with B=ones (lands in same C-reg as acc_o).
// ---------------------------------------------------------------------------
__global__ void __launch_bounds__(256, 2) attn_kernel(
    const unsigned short* __restrict__ Qb, const unsigned short* __restrict__ Kb,
    const unsigned short* __restrict__ Vt, const unsigned long long* __restrict__ mbits,
    unsigned short* __restrict__ ctx) {
  __shared__ __align__(16) unsigned short Ks[2][128 * 64];
  __shared__ __align__(16) unsigned short Vs[2][64 * 128];
  const int tid = threadIdx.x;
  const int lane = tid & 63, wv = tid >> 6;
  const int l31 = lane & 31, h = lane >> 5;
  const int pair = blockIdx.x >> 4, qt = blockIdx.x & 15;
  const int b_ = pair >> 4, hd = pair & 15;
  const int qg = qt * 128 + wv * 32 + l31;          // this lane's q row
  const size_t pbase = (size_t)pair * (2048 * 64);

  // loop-invariant staging assignments (256 threads stage 128x64 K + 64x128 V)
  int kofs[4], vofs[4];
  const unsigned short* kgp[4];
  const unsigned short* vgp[4];
#pragma unroll
  for (int it = 0; it < 4; ++it) {
    const int ch = it * 256 + tid;
    const int kr = ch >> 3, kc = ch & 7;
    kofs[it] = kr * 64 + ((kc ^ (kr & 7)) * 8);
    kgp[it] = Kb + pbase + (size_t)kr * 64 + kc * 8;     // += 8192 per kb
    const int vr = ch >> 4, vc = ch & 15;
    vofs[it] = vr * 128 + ((vc ^ ((vr & 7) << 1)) * 8);
    vgp[it] = Vt + pbase + (size_t)vr * 2048 + vc * 8;   // += 128 per kb
  }

  // Q B-frags (pre-scaled in qkv_gemm): B[k=h*8+j][n=l31]
  short8 qf[4];
#pragma unroll
  for (int ks = 0; ks < 4; ++ks)
    qf[ks] = *(const short8*)(Qb + pbase + (size_t)qg * 64 + ks * 16 + h * 8);

  union { unsigned short u[8]; short8 s8; } one_u;
#pragma unroll
  for (int i = 0; i < 8; ++i) one_u.u[i] = 0x3F80;  // bf16 1.0
  const short8 ones = one_u.s8;

  floatx16 NCv;
#pragma unroll
  for (int r = 0; r < 16; ++r) NCv[r] = -10.0f;     // fixed log2-domain shift

  floatx16 acc_o[2] = {};
  floatx16 acc_sum = {};

  // prefetch tile 0
  short8 kr8[4], vr8[4];
#pragma unroll
  for (int it = 0; it < 4; ++it) {
    kr8[it] = *(const short8*)kgp[it];
    vr8[it] = *(const short8*)vgp[it];
  }

  for (int kb16 = 0; kb16 < 16; ++kb16) {
    unsigned short* ksb = Ks[kb16 & 1];
    unsigned short* vsb = Vs[kb16 & 1];
#pragma unroll
    for (int it = 0; it < 4; ++it) {
      *(short8*)&ksb[kofs[it]] = kr8[it];
      *(short8*)&vsb[vofs[it]] = vr8[it];
    }
    __syncthreads();
    if (kb16 < 15) {  // prefetch next tile AFTER the barrier
      const size_t ko = (size_t)(kb16 + 1) * 8192;
      const size_t vo = (size_t)(kb16 + 1) * 128;
#pragma unroll
      for (int it = 0; it < 4; ++it) {
        kr8[it] = *(const short8*)(kgp[it] + ko);
        vr8[it] = *(const short8*)(vgp[it] + vo);
      }
    }

    // mask words for this lane's q row
    const unsigned long long* mrow = mbits + ((size_t)b_ * 2048 + qg) * 32 + kb16 * 2;
    const unsigned long long w0 = mrow[0], w1 = mrow[1];
    const bool anymask = __any((w0 & w1) != ~0ull);

#pragma unroll
    for (int kb = 0; kb < 4; ++kb) {
      // St = K·Q^T for this 32-k block; C: row=k_local, col=q=l31
      floatx16 accs;
      {
        const int krow = kb * 32 + l31;
        short8 kf = *(const short8*)&ksb[krow * 64 + ((h ^ (krow & 7)) * 8)];
        accs = __builtin_amdgcn_mfma_f32_32x32x16_bf16(kf, qf[0], NCv, 0, 0, 0);
#pragma unroll
        for (int ks = 1; ks < 4; ++ks) {
          short8 kf2 = *(const short8*)&ksb[krow * 64 + (((ks * 2 + h) ^ (krow & 7)) * 8)];
          accs = __builtin_amdgcn_mfma_f32_32x32x16_bf16(kf2, qf[ks], accs, 0, 0, 0);
        }
      }
      if (anymask) {
        const unsigned long long w = (kb < 2) ? w0 : w1;
#pragma unroll
        for (int reg = 0; reg < 16; ++reg) {
          const int kl = (reg & 3) + 8 * (reg >> 2) + 4 * h;
          const int bit = (kb & 1) * 32 + kl;
          if (!((w >> bit) & 1ull)) accs[reg] = -1e9f;
        }
      }
      // p = exp2(accs) (Q pre-scaled, -10 pre-seeded); pack to bf16 pairs
      unsigned int pk[8];
#pragma unroll
      for (int i = 0; i < 8; ++i)
        pk[i] = pkbf2(exp2f(accs[2 * i]), exp2f(accs[2 * i + 1]));

      // transit C-regs -> PV A-frags (lane half-swap), then PV + ones-rowsum
#pragma unroll
      for (int u = 0; u < 2; ++u) {
        const unsigned int own0 = h ? pk[4 * u + 2] : pk[4 * u + 0];
        const unsigned int own1 = h ? pk[4 * u + 3] : pk[4 * u + 1];
        const unsigned int snd0 = h ? pk[4 * u + 0] : pk[4 * u + 2];
        const unsigned int snd1 = h ? pk[4 * u + 1] : pk[4 * u + 3];
        const unsigned int t0 = __shfl_xor(snd0, 32);
        const unsigned int t1 = __shfl_xor(snd1, 32);
        union { unsigned int w[4]; short8 s8; } af;
        af.w[0] = h ? t0 : own0;
        af.w[1] = h ? t1 : own1;
        af.w[2] = h ? own0 : t0;
        af.w[3] = h ? own1 : t1;
        const int t = kb * 2 + u;  // PV k-step (16 s-rows each)
#pragma unroll
        for (int nt = 0; nt < 2; ++nt) {
          const int vrow = nt * 32 + l31;
          short8 vf = *(const short8*)&vsb[vrow * 128 + (((t * 2 + h) ^ ((vrow & 7) << 1)) * 8)];
          acc_o[nt] = __builtin_amdgcn_mfma_f32_32x32x16_bf16(af.s8, vf, acc_o[nt], 0, 0, 0);
        }
        acc_sum = __builtin_amdgcn_mfma_f32_32x32x16_bf16(af.s8, ones, acc_sum, 0, 0, 0);
      }
    }
  }

  // epilogue: row-sum sits in the SAME reg slot as acc_o -> no shuffles
#pragma unroll
  for (int reg = 0; reg < 16; ++reg) {
    const float s = acc_sum[reg];
    const float rinv = (s > 0.f) ? 1.f / s : 1.f;
    const int ql = (reg & 3) + 8 * (reg >> 2) + 4 * h;
    const size_t base = ((size_t)b_ * 2048 + qt * 128 + wv * 32 + ql) * 1024 + hd * 64;
    ctx[base + l31]      = f2bf(acc_o[0][reg] * rinv);
    ctx[base + 32 + l31] = f2bf(acc_o[1][reg] * rinv);
  }
}

// ---------------------------------------------------------------------------
// Kernel 4: output projection. out[m][e] = sum_d ctx[m][d]*Wo[e][d] + bo[e]
//   M=4096, N=1024, fp32 output.
// ---------------------------------------------------------------------------
__global__ void __launch_bounds__(256) out_gemm(
    const unsigned short* __restrict__ C, const unsigned short* __restrict__ W,
    const float* __restrict__ bo, float* __restrict__ out) {
  __shared__ __align__(16) unsigned short As[128 * 32];
  __shared__ __align__(16) unsigned short Bs[128 * 32];
  const int tid = threadIdx.x;
  const int lane = tid & 63, wv = tid >> 6;
  const int wm = wv >> 1, wn = wv & 1;
  const int quad = lane >> 4, l15 = lane & 15;
  const int mb = blockIdx.y, nb = blockIdx.x;

  const unsigned short* ga = C + (size_t)(mb * 128 + (tid >> 2)) * 1024 + (tid & 3) * 8;
  const unsigned short* gb = W + (size_t)(nb * 128 + (tid >> 2)) * 1024 + (tid & 3) * 8;
  unsigned short* la1 = As + tid * 8;
  unsigned short* la2 = As + 2048 + tid * 8;
  unsigned short* lb1 = Bs + tid * 8;
  unsigned short* lb2 = Bs + 2048 + tid * 8;

  floatx4 acc[4][4] = {};
  for (int kt = 0; kt < 32; ++kt) {
    const int k0 = kt * 32;
    gload16(ga + k0, la1);
    gload16(ga + k0 + 65536, la2);
    gload16(gb + k0, lb1);
    gload16(gb + k0 + 65536, lb2);
    __syncthreads();
    short8 af[4], bfr[4];
#pragma unroll
    for (int i = 0; i < 4; ++i) {
      af[i]  = *(const short8*)&As[(wm * 64 + i * 16 + l15) * 32 + quad * 8];
      bfr[i] = *(const short8*)&Bs[(wn * 64 + i * 16 + l15) * 32 + quad * 8];
    }
#pragma unroll
    for (int mt = 0; mt < 4; ++mt)
#pragma unroll
      for (int nt = 0; nt < 4; ++nt)
        acc[mt][nt] = __builtin_amdgcn_mfma_f32_16x16x32_bf16(af[mt], bfr[nt], acc[mt][nt], 0, 0, 0);
    __syncthreads();
  }
#pragma unroll
  for (int nt = 0; nt < 4; ++nt) {
    const int col = nb * 128 + wn * 64 + nt * 16 + l15;
    const float bias = bo[col];
#pragma unroll
    for (int mt = 0; mt < 4; ++mt)
#pragma unroll
      for (int r = 0; r < 4; ++r) {
        const int row = mb * 128 + wm * 64 + mt * 16 + quad * 4 + r;
        out[(size_t)row * 1024 + col] = acc[mt][nt][r] + bias;
      }
  }
}

// ---------------------------------------------------------------------------
extern "C" void kernel_launch(void* const* d_in, const int* in_sizes, int n_in,
                              void* d_out, int out_size, void* d_ws, size_t ws_size,
                              hipStream_t stream) {
  const float* hs = (const float*)d_in[0];
  const int* mask = (const int*)d_in[1];
  const float* Wq = (const float*)d_in[2];
  const float* bq = (const float*)d_in[3];
  const float* Wk = (const float*)d_in[4];
  const float* bk = (const float*)d_in[5];
  const float* Wv = (const float*)d_in[6];
  const float* bv = (const float*)d_in[7];
  const float* Wo = (const float*)d_in[8];
  const float* bo = (const float*)d_in[9];
  float* out = (float*)d_out;

  char* ws = (char*)d_ws;
  unsigned short* xbf  = (unsigned short*)(ws + 0);          // 4M elems
  unsigned short* wqkv = (unsigned short*)(ws + 8388608);    // 3M
  unsigned short* wobf = (unsigned short*)(ws + 14680064);   // 1M
  unsigned short* Qb   = (unsigned short*)(ws + 16777216);   // 4M
  unsigned short* Kb   = (unsigned short*)(ws + 25165824);   // 4M
  unsigned short* Vt   = (unsigned short*)(ws + 33554432);   // 4M
  unsigned short* ctx  = (unsigned short*)(ws + 41943040);   // 4M
  unsigned long long* mbits = (unsigned long long*)(ws + 50331648);  // 131072 words

  prep_kernel<<<8704, 256, 0, stream>>>(hs, Wq, Wk, Wv, Wo, mask, xbf, wqkv, wobf, mbits);
  qkv_gemm<<<dim3(24, 32), 256, 0, stream>>>(xbf, wqkv, bq, bk, bv, Qb, Kb, Vt);
  attn_kernel<<<512, 256, 0, stream>>>(Qb, Kb, Vt, mbits, ctx);
  out_gemm<<<dim3(8, 32), 256, 0, stream>>>(ctx, wobf, bo, out);
}

// Round 6
// 273.526 us; speedup vs baseline: 1.0182x; 1.0182x over previous
//
#include <hip/hip_runtime.h>

typedef short short8 __attribute__((ext_vector_type(8)));
typedef float floatx4 __attribute__((ext_vector_type(4)));
typedef float floatx16 __attribute__((ext_vector_type(16)));
typedef unsigned short ushort4v __attribute__((ext_vector_type(4)));

#define DEV static __device__ __forceinline__

// fp32 -> bf16 round-to-nearest-even
DEV unsigned short f2bf(float f) {
  unsigned int u = __builtin_bit_cast(unsigned int, f);
  u += 0x7fffu + ((u >> 16) & 1u);
  return (unsigned short)(u >> 16);
}

// pack two fp32 -> bf16x2 (round-half-up; P values positive, bias ~0.5 ulp)
DEV unsigned int pkbf2(float a, float b) {
  unsigned int ua = __builtin_bit_cast(unsigned int, a) + 0x8000u;
  unsigned int ub = __builtin_bit_cast(unsigned int, b) + 0x8000u;
  return (ua >> 16) | (ub & 0xffff0000u);
}

// async global->LDS, 16B per lane (dest = wave-uniform base + lane*16)
DEV void gload16(const unsigned short* g, unsigned short* l) {
  __builtin_amdgcn_global_load_lds((__attribute__((address_space(1))) void*)g,
                                   (__attribute__((address_space(3))) void*)l,
                                   16, 0, 0);
}

// ---------------------------------------------------------------------------
// Kernel 1: fused fp32->bf16 convert (blocks 0..8191) + maskpack (8192..8703)
// ---------------------------------------------------------------------------
__global__ void prep_kernel(const float* __restrict__ hs, const float* __restrict__ Wq,
                            const float* __restrict__ Wk, const float* __restrict__ Wv,
                            const float* __restrict__ Wo, const int* __restrict__ mask,
                            unsigned short* __restrict__ xbf, unsigned short* __restrict__ wqkv,
                            unsigned short* __restrict__ wobf,
                            unsigned long long* __restrict__ bits) {
  const int bid = blockIdx.x;
  if (bid < 8192) {
    size_t i4 = ((size_t)bid * 256 + threadIdx.x) * 4;
    const float* src;
    unsigned short* dst;
    if (i4 < 4194304) {
      src = hs + i4; dst = xbf + i4;
    } else if (i4 < 7340032) {
      size_t o = i4 - 4194304;
      size_t lo = o & 1048575;
      src = (o < 1048576) ? (Wq + lo) : ((o < 2097152) ? (Wk + lo) : (Wv + lo));
      dst = wqkv + o;
    } else {
      size_t o = i4 - 7340032;
      src = Wo + o; dst = wobf + o;
    }
    float4 v = *(const float4*)src;
    ushort4v u;
    u.x = f2bf(v.x); u.y = f2bf(v.y); u.z = f2bf(v.z); u.w = f2bf(v.w);
    *(ushort4v*)dst = u;
  } else {
    int w = (bid - 8192) * 256 + threadIdx.x;  // 131072 words
    const int4* p = (const int4*)(mask + (size_t)w * 64);
    unsigned long long r = 0ull;
#pragma unroll
    for (int j = 0; j < 16; ++j) {
      int4 m = p[j];
      r |= (unsigned long long)(m.x != 0) << (j * 4 + 0);
      r |= (unsigned long long)(m.y != 0) << (j * 4 + 1);
      r |= (unsigned long long)(m.z != 0) << (j * 4 + 2);
      r |= (unsigned long long)(m.w != 0) << (j * 4 + 3);
    }
    bits[w] = r;
  }
}

// ---------------------------------------------------------------------------
// Kernel 2: fused QKV projection. 64(M=s) x 128(N=Wcol) tile, BK=32, 4 waves.
//   grid (24, 64) = 1536 blocks -> 6 blocks/CU.
//   nb<16 (Q,K): swapped orientation: wave wv owns Wcol block [wv*32,+32) ->
//     d along regs -> packed 8B stores to [b,h,s,d]; Q pre-scaled log2(e)/8.
//   nb>=16 (V): normal: wm=wv>>1 (s), wn=wv&1 (Wcol) -> packed 8B V^T stores.
// ---------------------------------------------------------------------------
__global__ void __launch_bounds__(256, 2) qkv_gemm(
    const unsigned short* __restrict__ X, const unsigned short* __restrict__ W,
    const float* __restrict__ bq, const float* __restrict__ bk, const float* __restrict__ bv,
    unsigned short* __restrict__ Qb, unsigned short* __restrict__ Kb,
    unsigned short* __restrict__ Vt) {
  __shared__ __align__(16) unsigned short As[64 * 32];
  __shared__ __align__(16) unsigned short Bs[128 * 32];
  const int tid = threadIdx.x;
  const int lane = tid & 63, wv = tid >> 6;
  const int quad = lane >> 4, l15 = lane & 15;
  const int mb = blockIdx.y, nb = blockIdx.x;
  const bool sw = (nb < 16);

  const unsigned short* ga = X + (size_t)(mb * 64 + (tid >> 2)) * 1024 + (tid & 3) * 8;
  const unsigned short* gb = W + (size_t)(nb * 128 + (tid >> 2)) * 1024 + (tid & 3) * 8;
  unsigned short* la1 = As + tid * 8;
  unsigned short* lb1 = Bs + tid * 8;
  unsigned short* lb2 = Bs + 2048 + tid * 8;

  floatx4 acc[2][4] = {};
  for (int kt = 0; kt < 32; ++kt) {
    const int k0 = kt * 32;
    gload16(ga + k0, la1);
    gload16(gb + k0, lb1);
    gload16(gb + k0 + 65536, lb2);   // +64 rows of W
    __syncthreads();
    if (sw) {
      short8 wb[2], xa[4];
#pragma unroll
      for (int i = 0; i < 2; ++i)
        wb[i] = *(const short8*)&Bs[(wv * 32 + i * 16 + l15) * 32 + quad * 8];
#pragma unroll
      for (int i = 0; i < 4; ++i)
        xa[i] = *(const short8*)&As[(i * 16 + l15) * 32 + quad * 8];
#pragma unroll
      for (int mt = 0; mt < 2; ++mt)
#pragma unroll
        for (int nt = 0; nt < 4; ++nt)
          acc[mt][nt] = __builtin_amdgcn_mfma_f32_16x16x32_bf16(wb[mt], xa[nt], acc[mt][nt], 0, 0, 0);
    } else {
      const int wm = wv >> 1, wn = wv & 1;
      short8 xa[2], wb[4];
#pragma unroll
      for (int i = 0; i < 2; ++i)
        xa[i] = *(const short8*)&As[(wm * 32 + i * 16 + l15) * 32 + quad * 8];
#pragma unroll
      for (int i = 0; i < 4; ++i)
        wb[i] = *(const short8*)&Bs[(wn * 64 + i * 16 + l15) * 32 + quad * 8];
#pragma unroll
      for (int mt = 0; mt < 2; ++mt)
#pragma unroll
        for (int nt = 0; nt < 4; ++nt)
          acc[mt][nt] = __builtin_amdgcn_mfma_f32_16x16x32_bf16(xa[mt], wb[nt], acc[mt][nt], 0, 0, 0);
    }
    __syncthreads();
  }

  if (sw) {
    // C rows = Wcol, cols = s. d along regs -> packed stores.
#pragma unroll
    for (int mt = 0; mt < 2; ++mt) {
      const int wc0 = nb * 128 + wv * 32 + mt * 16 + quad * 4;
      const int mat = wc0 >> 10;          // 0=Q, 1=K
      const int nl0 = wc0 & 1023;
      const int hh = nl0 >> 6, d0 = nl0 & 63;
      const float4 b4 = *(const float4*)((mat ? bk : bq) + nl0);
      const float scl = mat ? 1.0f : 0.180336879f;  // Q pre-scale: log2(e)/8
      unsigned short* dst = mat ? Kb : Qb;
#pragma unroll
      for (int nt = 0; nt < 4; ++nt) {
        const int colx = mb * 64 + nt * 16 + l15;     // s index
        const int bb = colx >> 11, s = colx & 2047;
        ushort4v pv;
        pv[0] = f2bf((acc[mt][nt][0] + b4.x) * scl);
        pv[1] = f2bf((acc[mt][nt][1] + b4.y) * scl);
        pv[2] = f2bf((acc[mt][nt][2] + b4.z) * scl);
        pv[3] = f2bf((acc[mt][nt][3] + b4.w) * scl);
        *(ushort4v*)&dst[((size_t)(bb * 16 + hh) * 2048 + s) * 64 + d0] = pv;
      }
    }
  } else {
    const int wm = wv >> 1, wn = wv & 1;
#pragma unroll
    for (int nt = 0; nt < 4; ++nt) {
      const int col = nb * 128 + wn * 64 + nt * 16 + l15;  // in [2048,3072)
      const int nl = col & 1023;
      const float bias = bv[nl];
      const int hh = nl >> 6, d = nl & 63;
#pragma unroll
      for (int mt = 0; mt < 2; ++mt) {
        const int row0 = mb * 64 + wm * 32 + mt * 16 + quad * 4;
        const int bb = row0 >> 11, s = row0 & 2047;
        ushort4v pv;
#pragma unroll
        for (int r = 0; r < 4; ++r) pv[r] = f2bf(acc[mt][nt][r] + bias);
        *(ushort4v*)&Vt[((size_t)(bb * 16 + hh) * 64 + d) * 2048 + s] = pv;
      }
    }
  }
}

// ---------------------------------------------------------------------------
// Kernel 3: flash attention. 1024 blocks = 32 (b,h) x 32 q-tiles of 64;
//   2 waves x 32 q-rows; 32KB LDS single-buffer -> 4 blocks/CU, 8 waves/CU.
//   K/V staged by global_load_lds with the XOR swizzle folded into the
//   per-lane SOURCE address (swizzle is row-local -> lane mapping invariant).
//   Q pre-scaled; -10 shift seeded via MFMA C-operand; row-sum via ones-MFMA.
// ---------------------------------------------------------------------------
__global__ void __launch_bounds__(128, 2) attn_kernel(
    const unsigned short* __restrict__ Qb, const unsigned short* __restrict__ Kb,
    const unsigned short* __restrict__ Vt, const unsigned long long* __restrict__ mbits,
    unsigned short* __restrict__ ctx) {
  __shared__ __align__(16) unsigned short Ks[128 * 64];   // [row][chunk c^(row&7)]
  __shared__ __align__(16) unsigned short Vs[64 * 128];   // [d][chunk c^((d&7)<<1)]
  const int tid = threadIdx.x;            // 0..127
  const int lane = tid & 63, wv = tid >> 6;
  const int l31 = lane & 31, h = lane >> 5;
  const int pair = blockIdx.x >> 5, qt = blockIdx.x & 31;
  const int b_ = pair >> 4, hd = pair & 15;
  const int qg = qt * 64 + wv * 32 + l31;           // this lane's q row
  const size_t pbase = (size_t)pair * (2048 * 64);

  // per-lane staging source bases (swizzle folded in):
  // K: chunk ch = g*128 + wv*64 + lane; row=ch>>3, pc=ch&7, src c = pc^(row&7)
  const int krl = lane >> 3;                         // row low bits (row&7 == krl&7)
  const unsigned short* pkK = Kb + pbase + (size_t)(wv * 8 + krl) * 64 +
                              (((lane & 7) ^ (krl & 7)) * 8);
  // V: ch>>4 = g*8 + wv*4 + (lane>>4); pc = lane&15; src c = pc ^ ((row&7)<<1)
  const int vrl = wv * 4 + (lane >> 4);
  const unsigned short* pkV = Vt + pbase + (size_t)vrl * 2048 +
                              (((lane & 15) ^ ((vrl & 7) << 1)) * 8);

  // Q B-frags (pre-scaled in qkv_gemm): B[k=..][n=l31]
  short8 qf[4];
#pragma unroll
  for (int ks = 0; ks < 4; ++ks)
    qf[ks] = *(const short8*)(Qb + pbase + (size_t)qg * 64 + ks * 16 + h * 8);

  union { unsigned short u[8]; short8 s8; } one_u;
#pragma unroll
  for (int i = 0; i < 8; ++i) one_u.u[i] = 0x3F80;  // bf16 1.0
  const short8 ones = one_u.s8;

  floatx16 NCv;
#pragma unroll
  for (int r = 0; r < 16; ++r) NCv[r] = -10.0f;     // fixed log2-domain shift

  floatx16 acc_o[2] = {};
  floatx16 acc_sum = {};

  for (int kb16 = 0; kb16 < 16; ++kb16) {
    // stage this iter's K/V tiles straight to (swizzled) LDS
#pragma unroll
    for (int g = 0; g < 8; ++g)
      gload16(pkK + (size_t)kb16 * 8192 + g * 1024, Ks + (g * 128 + wv * 64) * 8);
#pragma unroll
    for (int g = 0; g < 8; ++g)
      gload16(pkV + (size_t)kb16 * 128 + g * 16384, Vs + (g * 128 + wv * 64) * 8);
    __syncthreads();   // drains vmcnt -> LDS tiles complete, all waves synced

    // mask words for this lane's q row
    const unsigned long long* mrow = mbits + ((size_t)b_ * 2048 + qg) * 32 + kb16 * 2;
    const unsigned long long w0 = mrow[0], w1 = mrow[1];
    const bool anymask = __any((w0 & w1) != ~0ull);

#pragma unroll
    for (int kb = 0; kb < 4; ++kb) {
      // St = K·Q^T for this 32-k block; C: row=k_local, col=q=l31
      floatx16 accs;
      {
        const int krow = kb * 32 + l31;
        short8 kf = *(const short8*)&Ks[krow * 64 + ((h ^ (krow & 7)) * 8)];
        accs = __builtin_amdgcn_mfma_f32_32x32x16_bf16(kf, qf[0], NCv, 0, 0, 0);
#pragma unroll
        for (int ks = 1; ks < 4; ++ks) {
          short8 kf2 = *(const short8*)&Ks[krow * 64 + (((ks * 2 + h) ^ (krow & 7)) * 8)];
          accs = __builtin_amdgcn_mfma_f32_32x32x16_bf16(kf2, qf[ks], accs, 0, 0, 0);
        }
      }
      if (anymask) {
        const unsigned long long w = (kb < 2) ? w0 : w1;
#pragma unroll
        for (int reg = 0; reg < 16; ++reg) {
          const int kl = (reg & 3) + 8 * (reg >> 2) + 4 * h;
          const int bit = (kb & 1) * 32 + kl;
          if (!((w >> bit) & 1ull)) accs[reg] = -1e9f;
        }
      }
      // p = exp2(accs); pack to bf16 pairs
      unsigned int pk[8];
#pragma unroll
      for (int i = 0; i < 8; ++i)
        pk[i] = pkbf2(exp2f(accs[2 * i]), exp2f(accs[2 * i + 1]));

      // C-regs -> PV A-frags (lane half-swap), then PV + ones-rowsum
#pragma unroll
      for (int u = 0; u < 2; ++u) {
        const unsigned int own0 = h ? pk[4 * u + 2] : pk[4 * u + 0];
        const unsigned int own1 = h ? pk[4 * u + 3] : pk[4 * u + 1];
        const unsigned int snd0 = h ? pk[4 * u + 0] : pk[4 * u + 2];
        const unsigned int snd1 = h ? pk[4 * u + 1] : pk[4 * u + 3];
        const unsigned int t0 = __shfl_xor(snd0, 32);
        const unsigned int t1 = __shfl_xor(snd1, 32);
        union { unsigned int w[4]; short8 s8; } af;
        af.w[0] = h ? t0 : own0;
        af.w[1] = h ? t1 : own1;
        af.w[2] = h ? own0 : t0;
        af.w[3] = h ? own1 : t1;
        const int t = kb * 2 + u;  // PV k-step (16 s-rows each)
#pragma unroll
        for (int nt = 0; nt < 2; ++nt) {
          const int vrow = nt * 32 + l31;
          short8 vf = *(const short8*)&Vs[vrow * 128 + (((t * 2 + h) ^ ((vrow & 7) << 1)) * 8)];
          acc_o[nt] = __builtin_amdgcn_mfma_f32_32x32x16_bf16(af.s8, vf, acc_o[nt], 0, 0, 0);
        }
        acc_sum = __builtin_amdgcn_mfma_f32_32x32x16_bf16(af.s8, ones, acc_sum, 0, 0, 0);
      }
    }
    __syncthreads();   // all reads done before next overwrite
  }

  // epilogue: row-sum sits in the SAME reg slot as acc_o -> no shuffles
#pragma unroll
  for (int reg = 0; reg < 16; ++reg) {
    const float s = acc_sum[reg];
    const float rinv = (s > 0.f) ? 1.f / s : 1.f;
    const int ql = (reg & 3) + 8 * (reg >> 2) + 4 * h;
    const size_t base = ((size_t)b_ * 2048 + qt * 64 + wv * 32 + ql) * 1024 + hd * 64;
    ctx[base + l31]      = f2bf(acc_o[0][reg] * rinv);
    ctx[base + 32 + l31] = f2bf(acc_o[1][reg] * rinv);
  }
}

// ---------------------------------------------------------------------------
// Kernel 4: output projection. 64(M) x 128(N) tile, BK=32, 4 waves.
//   grid (8, 64) = 512 blocks -> 2 blocks/CU (was 1 at 128x128).
// ---------------------------------------------------------------------------
__global__ void __launch_bounds__(256, 2) out_gemm(
    const unsigned short* __restrict__ C, const unsigned short* __restrict__ W,
    const float* __restrict__ bo, float* __restrict__ out) {
  __shared__ __align__(16) unsigned short As[64 * 32];
  __shared__ __align__(16) unsigned short Bs[128 * 32];
  const int tid = threadIdx.x;
  const int lane = tid & 63, wv = tid >> 6;
  const int wm = wv >> 1, wn = wv & 1;
  const int quad = lane >> 4, l15 = lane & 15;
  const int mb = blockIdx.y, nb = blockIdx.x;

  const unsigned short* ga = C + (size_t)(mb * 64 + (tid >> 2)) * 1024 + (tid & 3) * 8;
  const unsigned short* gb = W + (size_t)(nb * 128 + (tid >> 2)) * 1024 + (tid & 3) * 8;
  unsigned short* la1 = As + tid * 8;
  unsigned short* lb1 = Bs + tid * 8;
  unsigned short* lb2 = Bs + 2048 + tid * 8;

  floatx4 acc[2][4] = {};
  for (int kt = 0; kt < 32; ++kt) {
    const int k0 = kt * 32;
    gload16(ga + k0, la1);
    gload16(gb + k0, lb1);
    gload16(gb + k0 + 65536, lb2);
    __syncthreads();
    short8 af[2], bfr[4];
#pragma unroll
    for (int i = 0; i < 2; ++i)
      af[i] = *(const short8*)&As[(wm * 32 + i * 16 + l15) * 32 + quad * 8];
#pragma unroll
    for (int i = 0; i < 4; ++i)
      bfr[i] = *(const short8*)&Bs[(wn * 64 + i * 16 + l15) * 32 + quad * 8];
#pragma unroll
    for (int mt = 0; mt < 2; ++mt)
#pragma unroll
      for (int nt = 0; nt < 4; ++nt)
        acc[mt][nt] = __builtin_amdgcn_mfma_f32_16x16x32_bf16(af[mt], bfr[nt], acc[mt][nt], 0, 0, 0);
    __syncthreads();
  }
#pragma unroll
  for (int nt = 0; nt < 4; ++nt) {
    const int col = nb * 128 + wn * 64 + nt * 16 + l15;
    const float bias = bo[col];
#pragma unroll
    for (int mt = 0; mt < 2; ++mt)
#pragma unroll
      for (int r = 0; r < 4; ++r) {
        const int row = mb * 64 + wm * 32 + mt * 16 + quad * 4 + r;
        out[(size_t)row * 1024 + col] = acc[mt][nt][r] + bias;
      }
  }
}

// ---------------------------------------------------------------------------
extern "C" void kernel_launch(void* const* d_in, const int* in_sizes, int n_in,
                              void* d_out, int out_size, void* d_ws, size_t ws_size,
                              hipStream_t stream) {
  const float* hs = (const float*)d_in[0];
  const int* mask = (const int*)d_in[1];
  const float* Wq = (const float*)d_in[2];
  const float* bq = (const float*)d_in[3];
  const float* Wk = (const float*)d_in[4];
  const float* bk = (const float*)d_in[5];
  const float* Wv = (const float*)d_in[6];
  const float* bv = (const float*)d_in[7];
  const float* Wo = (const float*)d_in[8];
  const float* bo = (const float*)d_in[9];
  float* out = (float*)d_out;

  char* ws = (char*)d_ws;
  unsigned short* xbf  = (unsigned short*)(ws + 0);          // 4M elems
  unsigned short* wqkv = (unsigned short*)(ws + 8388608);    // 3M
  unsigned short* wobf = (unsigned short*)(ws + 14680064);   // 1M
  unsigned short* Qb   = (unsigned short*)(ws + 16777216);   // 4M
  unsigned short* Kb   = (unsigned short*)(ws + 25165824);   // 4M
  unsigned short* Vt   = (unsigned short*)(ws + 33554432);   // 4M
  unsigned short* ctx  = (unsigned short*)(ws + 41943040);   // 4M
  unsigned long long* mbits = (unsigned long long*)(ws + 50331648);  // 131072 words

  prep_kernel<<<8704, 256, 0, stream>>>(hs, Wq, Wk, Wv, Wo, mask, xbf, wqkv, wobf, mbits);
  qkv_gemm<<<dim3(24, 64), 256, 0, stream>>>(xbf, wqkv, bq, bk, bv, Qb, Kb, Vt);
  attn_kernel<<<1024, 128, 0, stream>>>(Qb, Kb, Vt, mbits, ctx);
  out_gemm<<<dim3(8, 64), 256, 0, stream>>>(ctx, wobf, bo, out);
}